// Round 5
// baseline (114.489 us; speedup 1.0000x reference)
//
#include <hip/hip_runtime.h>
#include <cstdint>
#include <cstddef>

namespace {
constexpr int kN    = 65536;     // nodes
constexpr int kF    = 256;       // feats
constexpr int kC    = 64;        // pools per graph
constexpr int kNPG  = 1024;      // nodes per graph
constexpr int kB    = 64;        // graphs
constexpr int kE    = 2097152;   // edges
constexpr int kK    = kB * kC;   // 4096 global clusters

// d_out offsets (in floats)
constexpr size_t OFF_OUT  = 0;                           // [4096,256]
constexpr size_t OFF_EIDX = (size_t)kK * kF;             // 1048576  [2,262144]
constexpr size_t OFF_ADJ  = OFF_EIDX + 2ull*kB*kC*kC;    // 1572864  [262144]
constexpr size_t OFF_LL   = OFF_ADJ + (size_t)kB*kC*kC;  // 1835008
constexpr size_t OFF_Z    = OFF_LL + 1;                  // 1835009
constexpr size_t OFF_BOUT = OFF_Z + 1;                   // 1835010  [4096]
constexpr size_t OFF_BPTR = OFF_BOUT + kK;               // 1839106  [65]

// ws offsets (bytes). PERM/START overlap PADJ (stream-disjoint lifetimes).
constexpr size_t WS_C    = 0;        // int[65536]
constexpr size_t WS_V    = 262144;   // float[65536]
constexpr size_t WS_VS2  = 524288;   // float[4096]
constexpr size_t WS_A2   = 540672;   // float[256]
constexpr size_t WS_PERM = 544768;   // int[65536]   (dead after k_pool_x)
constexpr size_t WS_STRT = 806912;   // int[64*65]   (dead after k_pool_x)
constexpr size_t WS_PADJ = 544768;   // float[256*4096] = 4 MiB (k_adj onward)
} // namespace

// ---------------------------------------------------------------- constants
__global__ __launch_bounds__(256) void k_const(float* __restrict__ out)
{
    const int i = blockIdx.x * 256 + threadIdx.x;
    constexpr int E2 = 2 * kB * kC * kC;      // 524288
    if (i < E2) {
        const int half = i >= kB*kC*kC;
        const int idx  = half ? i - kB*kC*kC : i;
        const int bb = idx >> 12, rem = idx & 4095;
        const int val = half ? bb*kC + (rem & 63) : bb*kC + (rem >> 6);
        out[OFF_EIDX + i] = (float)val;
    } else if (i < E2 + kK) {
        const int j = i - E2;
        out[OFF_BOUT + j] = (float)(j >> 6);
    } else if (i < E2 + kK + kB + 1) {
        const int j = i - (E2 + kK);
        out[OFF_BPTR + j] = (float)(j * kC);
    }
}

// ------------------------------------------------- K1: logits -> c, v
// GEMM M=65536 N=64 K=256. 64-thread (1-wave) blocks, BM=64 nodes, 8x8 reg
// tile. grid=1024 -> 4 independent waves/CU (no cross-wave barriers; stage
// latency of one wave hides under the others' compute).
// LDS xs: [k][node], stride 68 -> fragment b128 reads 2-way (free),
// transpose scalar writes 4-way (1.58x, only 64/thread/chunk).
__global__ __launch_bounds__(64) void k_logits(
    const float* __restrict__ x, const float* __restrict__ Wm,
    const float* __restrict__ bv, int* __restrict__ carr,
    float* __restrict__ varr)
{
    constexpr int BM = 64, KC = 64, BMP = 68;
    __shared__ float xs[KC * BMP];    // 17408 B, [k][node]
    __shared__ float wsd[KC * kC];    // 16384 B, [k][c]
    const int tid = threadIdx.x;      // 0..63
    const int tx  = tid & 7;          // col group: cols tx*8 .. +7
    const int ty  = tid >> 3;         // node group: nodes ty*8 .. +7
    const int nbase = blockIdx.x * BM;

    float acc[8][8];
#pragma unroll
    for (int j = 0; j < 8; ++j) {
        const float bb = bv[tx*8 + j];
#pragma unroll
        for (int i = 0; i < 8; ++i) acc[i][j] = bb;
    }

    for (int kc = 0; kc < kF; kc += KC) {
        __syncthreads();
        // ---- stage W chunk: 64k x 64c, float4 writes (2-way, free)
#pragma unroll
        for (int r = 0; r < 16; ++r) {
            const int idx = r*64 + tid;          // 0..1023 float4 slots
            const int k = idx >> 4, q = idx & 15;
            *reinterpret_cast<float4*>(&wsd[k*kC + q*4]) =
                *reinterpret_cast<const float4*>(
                    Wm + (size_t)(kc + k)*kC + q*4);
        }
        // ---- stage x chunk transposed: [k][node]
#pragma unroll
        for (int r = 0; r < 16; ++r) {
            const int idx  = r*64 + tid;         // 0..1023 float4 slots
            const int q3   = idx & 7;
            const int n3   = (idx >> 3) & 7;
            const int seg  = (idx >> 6) & 1;
            const int nhi  = idx >> 7;
            const int node = n3 + nhi*8;
            const int q    = q3 + seg*8;         // float4-slot along k
            const float4 g = *reinterpret_cast<const float4*>(
                x + (size_t)(nbase + node)*kF + kc + q*4);
            xs[(q*4+0)*BMP + node] = g.x;
            xs[(q*4+1)*BMP + node] = g.y;
            xs[(q*4+2)*BMP + node] = g.z;
            xs[(q*4+3)*BMP + node] = g.w;
        }
        __syncthreads();
        // ---- compute: per kk, 2 b128 x-frag + 2 b128 w-frag + 64 FMA
#pragma unroll 4
        for (int kk = 0; kk < KC; ++kk) {
            const float4 xa = *reinterpret_cast<const float4*>(
                &xs[kk*BMP + ty*8]);
            const float4 xb = *reinterpret_cast<const float4*>(
                &xs[kk*BMP + ty*8 + 4]);
            const float4 wa = *reinterpret_cast<const float4*>(
                &wsd[kk*kC + tx*8]);
            const float4 wb = *reinterpret_cast<const float4*>(
                &wsd[kk*kC + tx*8 + 4]);
            const float xv[8] = {xa.x, xa.y, xa.z, xa.w,
                                 xb.x, xb.y, xb.z, xb.w};
            const float wv[8] = {wa.x, wa.y, wa.z, wa.w,
                                 wb.x, wb.y, wb.z, wb.w};
#pragma unroll
            for (int i = 0; i < 8; ++i)
#pragma unroll
                for (int j = 0; j < 8; ++j)
                    acc[i][j] = fmaf(xv[i], wv[j], acc[i][j]);
        }
    }

    // per-node softmax-argmax over 64 cols spread across 8 tx-lanes x 8 regs
#pragma unroll
    for (int i = 0; i < 8; ++i) {
        float m = acc[i][0];
        int   ci = tx*8;
#pragma unroll
        for (int j = 1; j < 8; ++j)
            if (acc[i][j] > m) { m = acc[i][j]; ci = tx*8 + j; }
#pragma unroll
        for (int off = 1; off < 8; off <<= 1) {
            const float om = __shfl_xor(m, off);
            const int   oc = __shfl_xor(ci, off);
            if (om > m || (om == m && oc < ci)) { m = om; ci = oc; }
        }
        float s = 0.f;
#pragma unroll
        for (int j = 0; j < 8; ++j) s += expf(acc[i][j] - m);
#pragma unroll
        for (int off = 1; off < 8; off <<= 1) s += __shfl_xor(s, off);
        if (tx == 0) {
            const float p = 1.0f / s;
            const int n = nbase + ty*8 + i;
            carr[n] = ci;
            varr[n] = (1.0f - p) + p;   // straight-through forward value
        }
    }
}

// ------------------------------------- K1b: deterministic stable counting sort
__global__ __launch_bounds__(1024) void k_sort(
    const int* __restrict__ carr, int* __restrict__ perm,
    int* __restrict__ startc)
{
    __shared__ int hist[16][64];
    __shared__ int startS[65];
    const int g = blockIdx.x;
    const int tid = threadIdx.x;
    const int w = tid >> 6, lane = tid & 63;
    const int c = carr[g*kNPG + tid];
    hist[tid >> 6][tid & 63] = 0;
    __syncthreads();
    unsigned long long mm = ~0ull;
#pragma unroll
    for (int b = 0; b < 6; ++b) {
        const unsigned long long bal = __ballot((c >> b) & 1);
        mm &= ((c >> b) & 1) ? bal : ~bal;
    }
    const unsigned long long ltmask =
        (lane == 0) ? 0ull : (~0ull >> (64 - lane));
    const int rank_in_wave = __popcll(mm & ltmask);
    const int leader = __ffsll((unsigned long long)mm) - 1;
    if (lane == leader) hist[w][c] = __popcll(mm);
    __syncthreads();
    if (w == 0) {
        int tot = 0;
#pragma unroll
        for (int i = 0; i < 16; ++i) tot += hist[i][lane];
        int pre = tot;
#pragma unroll
        for (int off = 1; off < 64; off <<= 1) {
            const int t = __shfl_up(pre, off);
            if (lane >= off) pre += t;
        }
        startS[lane + 1] = pre;
        if (lane == 0) startS[0] = 0;
    }
    __syncthreads();
    int before = startS[c];
    for (int i = 0; i < w; ++i) before += hist[i][c];
    perm[g*kNPG + before + rank_in_wave] = g*kNPG + tid;
    if (tid < 65) startc[g*65 + tid] = startS[tid];
}

// ------------------------------------- K2: out = S^T x (+ vs2) — atomic-FREE
__global__ __launch_bounds__(1024) void k_pool_x(
    const float* __restrict__ x, const int* __restrict__ perm,
    const int* __restrict__ startc, const float* __restrict__ varr,
    float* __restrict__ out, float* __restrict__ vs2)
{
    const int tid  = threadIdx.x;
    const int g    = blockIdx.x >> 3;
    const int fh   = blockIdx.x & 7;
    const int w    = tid >> 6;
    const int lane = tid & 63;
    const int q    = lane & 7;      // feat quad (float4)
    const int sub  = lane >> 3;     // node slot 0..7
    const int fbase = fh*32 + q*4;
#pragma unroll
    for (int cc = 0; cc < 4; ++cc) {
        const int c = w*4 + cc;
        const int s = startc[g*65 + c];
        const int e = startc[g*65 + c + 1];
        float ax = 0.f, ay = 0.f, az = 0.f, aw = 0.f, v2 = 0.f;
        for (int base = s + sub; base < e; base += 8) {
            const int n = perm[(size_t)g*kNPG + base];
            const float v = varr[n];
            const float4 xv = *reinterpret_cast<const float4*>(
                x + (size_t)n*kF + fbase);
            ax = fmaf(v, xv.x, ax); ay = fmaf(v, xv.y, ay);
            az = fmaf(v, xv.z, az); aw = fmaf(v, xv.w, aw);
            v2 = fmaf(v, v, v2);
        }
#pragma unroll
        for (int off = 8; off < 64; off <<= 1) {
            ax += __shfl_xor(ax, off); ay += __shfl_xor(ay, off);
            az += __shfl_xor(az, off); aw += __shfl_xor(aw, off);
            v2 += __shfl_xor(v2, off);
        }
        if (sub == 0) {
            const float4 o = {ax, ay, az, aw};
            *reinterpret_cast<float4*>(
                out + OFF_OUT + (size_t)(g*kC + c)*kF + fbase) = o;
        }
        if (fh == 0 && lane == 0) vs2[g*kC + c] = v2;
    }
}

// ------------------------------------- K4: adjacency partials (+ a2 partial)
__global__ __launch_bounds__(1024) void k_adj(
    const int* __restrict__ ei, const float* __restrict__ ew,
    const int* __restrict__ carr, const float* __restrict__ varr,
    float* __restrict__ padj, float* __restrict__ a2p)
{
    __shared__ float adj[kC*kC];   // 16 KB
    __shared__ float vls[kNPG];    // 4 KB
    __shared__ int   cls[kNPG];    // 4 KB
    __shared__ float wred[16];
    const int tid = threadIdx.x;
    const int bid = blockIdx.x;             // 256 blocks = 64 graphs x 4
    const int g   = bid >> 2;
    for (int i = tid; i < kC*kC; i += 1024) adj[i] = 0.f;
    vls[tid] = varr[g*kNPG + tid];
    cls[tid] = carr[g*kNPG + tid];
    __syncthreads();
    const int e0 = bid * 8192;
    float a2l = 0.f;
#pragma unroll
    for (int it = 0; it < 8; ++it) {
        const int e  = e0 + it*1024 + tid;
        const int sn = ei[e]      & (kNPG - 1);
        const int dn = ei[kE + e] & (kNPG - 1);
        const float wv = ew[e];
        a2l += wv * wv;
        atomicAdd(&adj[cls[sn]*kC + cls[dn]], wv * vls[sn] * vls[dn]);
    }
    __syncthreads();
#pragma unroll
    for (int r = 0; r < 4; ++r) {
        const int lin = r*1024 + tid;
        padj[(size_t)bid*4096 + lin] = adj[lin];
    }
#pragma unroll
    for (int off = 32; off > 0; off >>= 1) a2l += __shfl_down(a2l, off);
    if ((tid & 63) == 0) wred[tid >> 6] = a2l;
    __syncthreads();
    if (tid == 0) {
        float s = 0.f;
#pragma unroll
        for (int wv = 0; wv < 16; ++wv) s += wred[wv];
        a2p[bid] = s;
    }
}

// ------------------------------------- K5: merge adjacency partials
__global__ __launch_bounds__(256) void k_adj_merge(
    const float* __restrict__ padj, float* __restrict__ out)
{
    const int id = blockIdx.x*256 + threadIdx.x;   // < 262144
    const int g = id >> 12, idx = id & 4095;
    float s = 0.f;
#pragma unroll
    for (int sp = 0; sp < 4; ++sp) s += padj[(size_t)(g*4 + sp)*4096 + idx];
    out[OFF_ADJ + id] = s;
}

// ------------------------------------- K6: link_loss scalar
__global__ __launch_bounds__(256) void k_final(
    const float* __restrict__ vs2, const float* __restrict__ a2p,
    float* __restrict__ out)
{
    const int tid = threadIdx.x;
    float p2l = 0.f, apl = 0.f;
#pragma unroll
    for (int r = 0; r < 16; ++r) {
        const int k = r*256 + tid;
        const float t = vs2[k];
        p2l += t*t;
        const int g = k >> 6, cc = k & 63;
        apl += out[OFF_ADJ + (size_t)g*4096 + cc*65];   // diagonal entries
    }
    float a2l = a2p[tid];
#pragma unroll
    for (int off = 32; off > 0; off >>= 1) {
        p2l += __shfl_down(p2l, off);
        apl += __shfl_down(apl, off);
        a2l += __shfl_down(a2l, off);
    }
    __shared__ float red[3][4];
    if ((tid & 63) == 0) {
        red[0][tid>>6] = p2l; red[1][tid>>6] = apl; red[2][tid>>6] = a2l;
    }
    __syncthreads();
    if (tid == 0) {
        const float p2 = red[0][0]+red[0][1]+red[0][2]+red[0][3];
        const float ap = red[1][0]+red[1][1]+red[1][2]+red[1][3];
        const float a2 = red[2][0]+red[2][1]+red[2][2]+red[2][3];
        const float val = a2 - 2.0f*ap + p2;
        out[OFF_LL] = sqrtf(fmaxf(val, 0.f)) / (float)kE;
        out[OFF_Z]  = 0.0f;
    }
}

// ----------------------------------------------------------------- launch
extern "C" void kernel_launch(void* const* d_in, const int* in_sizes, int n_in,
                              void* d_out, int out_size, void* d_ws, size_t ws_size,
                              hipStream_t stream)
{
    const float* x  = (const float*)d_in[0];
    const int*   ei = (const int*)d_in[1];
    const float* ew = (const float*)d_in[2];
    const float* Wm = (const float*)d_in[5];
    const float* bv = (const float*)d_in[6];
    float* out = (float*)d_out;
    char*  ws  = (char*)d_ws;
    int*   carr  = (int*)(ws + WS_C);
    float* varr  = (float*)(ws + WS_V);
    float* vs2   = (float*)(ws + WS_VS2);
    float* a2p   = (float*)(ws + WS_A2);
    int*   perm  = (int*)(ws + WS_PERM);
    int*   strt  = (int*)(ws + WS_STRT);
    float* padj  = (float*)(ws + WS_PADJ);

    k_const    <<<2065, 256, 0, stream>>>(out);
    k_logits   <<<1024,  64, 0, stream>>>(x, Wm, bv, carr, varr);
    k_sort     <<<64,  1024, 0, stream>>>(carr, perm, strt);
    k_pool_x   <<<512, 1024, 0, stream>>>(x, perm, strt, varr, out, vs2);
    k_adj      <<<256, 1024, 0, stream>>>(ei, ew, carr, varr, padj, a2p);
    k_adj_merge<<<1024, 256, 0, stream>>>(padj, out);
    k_final    <<<1,    256, 0, stream>>>(vs2, a2p, out);
}

// Round 6
// 111.567 us; speedup vs baseline: 1.0262x; 1.0262x over previous
//
#include <hip/hip_runtime.h>
#include <cstdint>
#include <cstddef>

namespace {
constexpr int kN    = 65536;     // nodes
constexpr int kF    = 256;       // feats
constexpr int kC    = 64;        // pools per graph
constexpr int kNPG  = 1024;      // nodes per graph
constexpr int kB    = 64;        // graphs
constexpr int kE    = 2097152;   // edges
constexpr int kK    = kB * kC;   // 4096 global clusters

// d_out offsets (in floats)
constexpr size_t OFF_OUT  = 0;                           // [4096,256]
constexpr size_t OFF_EIDX = (size_t)kK * kF;             // 1048576  [2,262144]
constexpr size_t OFF_ADJ  = OFF_EIDX + 2ull*kB*kC*kC;    // 1572864  [262144]
constexpr size_t OFF_LL   = OFF_ADJ + (size_t)kB*kC*kC;  // 1835008
constexpr size_t OFF_Z    = OFF_LL + 1;                  // 1835009
constexpr size_t OFF_BOUT = OFF_Z + 1;                   // 1835010  [4096]
constexpr size_t OFF_BPTR = OFF_BOUT + kK;               // 1839106  [65]

// ws offsets (bytes). PERM/START overlap PADJ (stream-disjoint lifetimes).
constexpr size_t WS_C    = 0;        // int[65536]
constexpr size_t WS_V    = 262144;   // float[65536]
constexpr size_t WS_VS2  = 524288;   // float[4096]
constexpr size_t WS_A2   = 540672;   // float[256]
constexpr size_t WS_PERM = 544768;   // int[65536]   (dead after k_pool_x)
constexpr size_t WS_STRT = 806912;   // int[64*65]   (dead after k_pool_x)
constexpr size_t WS_PADJ = 544768;   // float[256*4096] = 4 MiB (k_adj onward)
} // namespace

// ---------------------------------------------------------------- constants
__global__ __launch_bounds__(256) void k_const(float* __restrict__ out)
{
    const int i = blockIdx.x * 256 + threadIdx.x;
    constexpr int E2 = 2 * kB * kC * kC;      // 524288
    if (i < E2) {
        const int half = i >= kB*kC*kC;
        const int idx  = half ? i - kB*kC*kC : i;
        const int bb = idx >> 12, rem = idx & 4095;
        const int val = half ? bb*kC + (rem & 63) : bb*kC + (rem >> 6);
        out[OFF_EIDX + i] = (float)val;
    } else if (i < E2 + kK) {
        const int j = i - E2;
        out[OFF_BOUT + j] = (float)(j >> 6);
    } else if (i < E2 + kK + kB + 1) {
        const int j = i - (E2 + kK);
        out[OFF_BPTR + j] = (float)(j * kC);
    }
}

// ------------------------------------------------- K1: logits -> c, v
// GEMM M=65536 N=64 K=256. 1-wave blocks, BM=128, 8x16 reg tile:
// 6 b128 LDS reads per 128 FMA (r=1/21 ~ balanced vs LDS-pipe budget 1/24,
// and W reads are 16-way broadcast -> cheaper). LDS 16.9 KB -> 9 blocks/CU
// by LDS; VGPR ~170 -> 8 waves/CU = 2/SIMD (vs round-5's fatal 1/SIMD).
// Bank layout: x [k][node] with group-stride 12, row-stride 196 -> frag
// reads 2-way (free); W rows padded to 68 -> 2-way.
__global__ __launch_bounds__(64) void k_logits(
    const float* __restrict__ x, const float* __restrict__ Wm,
    const float* __restrict__ bv, int* __restrict__ carr,
    float* __restrict__ varr)
{
    constexpr int BM = 128, KC = 16, GSTR = 12, ROWSTR = 196, WSTR = 68;
    __shared__ float xs[KC * ROWSTR];   // 12544 B
    __shared__ float wsd[KC * WSTR];    // 4352 B
    const int tid = threadIdx.x;        // 0..63
    const int tx  = tid & 3;            // col group: cols tx*16 .. +15
    const int ty  = tid >> 2;           // node group: nodes ty*8 .. +7 (0..15)
    const int nbase = blockIdx.x * BM;

    float acc[8][16];
    {
        const float4 b0 = *reinterpret_cast<const float4*>(bv + tx*16);
        const float4 b1 = *reinterpret_cast<const float4*>(bv + tx*16 + 4);
        const float4 b2 = *reinterpret_cast<const float4*>(bv + tx*16 + 8);
        const float4 b3 = *reinterpret_cast<const float4*>(bv + tx*16 + 12);
        const float bb[16] = {b0.x,b0.y,b0.z,b0.w, b1.x,b1.y,b1.z,b1.w,
                              b2.x,b2.y,b2.z,b2.w, b3.x,b3.y,b3.z,b3.w};
#pragma unroll
        for (int i = 0; i < 8; ++i)
#pragma unroll
            for (int j = 0; j < 16; ++j) acc[i][j] = bb[j];
    }

#pragma unroll 1
    for (int kc = 0; kc < kF; kc += KC) {
        __syncthreads();
        // ---- stage W chunk: 16 k x 64 c
#pragma unroll
        for (int r = 0; r < 4; ++r) {
            const int idx = r*64 + tid;      // 0..255 float4 slots
            const int k = idx >> 4, q = idx & 15;
            *reinterpret_cast<float4*>(&wsd[k*WSTR + q*4]) =
                *reinterpret_cast<const float4*>(
                    Wm + (size_t)(kc + k)*kC + q*4);
        }
        // ---- stage x chunk transposed [k][node], group-stride 12
#pragma unroll
        for (int r = 0; r < 8; ++r) {
            const int idx  = r*64 + tid;     // 0..511 float4 slots
            const int node = idx >> 2;       // 0..127
            const int q    = idx & 3;        // k-quad
            const float4 g = *reinterpret_cast<const float4*>(
                x + (size_t)(nbase + node)*kF + kc + q*4);
            const int col = (node >> 3)*GSTR + (node & 7);
            xs[(q*4+0)*ROWSTR + col] = g.x;
            xs[(q*4+1)*ROWSTR + col] = g.y;
            xs[(q*4+2)*ROWSTR + col] = g.z;
            xs[(q*4+3)*ROWSTR + col] = g.w;
        }
        __syncthreads();
        // ---- compute: per kk: 2 b128 x-frag + 4 b128 w-frag + 128 FMA
#pragma unroll 4
        for (int kk = 0; kk < KC; ++kk) {
            const float4 xa = *reinterpret_cast<const float4*>(
                &xs[kk*ROWSTR + ty*GSTR]);
            const float4 xb = *reinterpret_cast<const float4*>(
                &xs[kk*ROWSTR + ty*GSTR + 4]);
            const float4 w0 = *reinterpret_cast<const float4*>(
                &wsd[kk*WSTR + tx*16]);
            const float4 w1 = *reinterpret_cast<const float4*>(
                &wsd[kk*WSTR + tx*16 + 4]);
            const float4 w2 = *reinterpret_cast<const float4*>(
                &wsd[kk*WSTR + tx*16 + 8]);
            const float4 w3 = *reinterpret_cast<const float4*>(
                &wsd[kk*WSTR + tx*16 + 12]);
            const float xv[8] = {xa.x, xa.y, xa.z, xa.w,
                                 xb.x, xb.y, xb.z, xb.w};
            const float wv[16] = {w0.x,w0.y,w0.z,w0.w, w1.x,w1.y,w1.z,w1.w,
                                  w2.x,w2.y,w2.z,w2.w, w3.x,w3.y,w3.z,w3.w};
#pragma unroll
            for (int i = 0; i < 8; ++i)
#pragma unroll
                for (int j = 0; j < 16; ++j)
                    acc[i][j] = fmaf(xv[i], wv[j], acc[i][j]);
        }
    }

    // per-node softmax-argmax: 64 cols spread across 4 tx-lanes x 16 regs
#pragma unroll
    for (int i = 0; i < 8; ++i) {
        float m = acc[i][0];
        int   ci = tx*16;
#pragma unroll
        for (int j = 1; j < 16; ++j)
            if (acc[i][j] > m) { m = acc[i][j]; ci = tx*16 + j; }
#pragma unroll
        for (int off = 1; off < 4; off <<= 1) {
            const float om = __shfl_xor(m, off);
            const int   oc = __shfl_xor(ci, off);
            if (om > m || (om == m && oc < ci)) { m = om; ci = oc; }
        }
        float s = 0.f;
#pragma unroll
        for (int j = 0; j < 16; ++j) s += expf(acc[i][j] - m);
#pragma unroll
        for (int off = 1; off < 4; off <<= 1) s += __shfl_xor(s, off);
        if (tx == 0) {
            const float p = 1.0f / s;
            const int n = nbase + ty*8 + i;
            carr[n] = ci;
            varr[n] = (1.0f - p) + p;   // straight-through forward value
        }
    }
}

// ------------------------------------- K1b: deterministic stable counting sort
__global__ __launch_bounds__(1024) void k_sort(
    const int* __restrict__ carr, int* __restrict__ perm,
    int* __restrict__ startc)
{
    __shared__ int hist[16][64];
    __shared__ int startS[65];
    const int g = blockIdx.x;
    const int tid = threadIdx.x;
    const int w = tid >> 6, lane = tid & 63;
    const int c = carr[g*kNPG + tid];
    hist[tid >> 6][tid & 63] = 0;
    __syncthreads();
    unsigned long long mm = ~0ull;
#pragma unroll
    for (int b = 0; b < 6; ++b) {
        const unsigned long long bal = __ballot((c >> b) & 1);
        mm &= ((c >> b) & 1) ? bal : ~bal;
    }
    const unsigned long long ltmask =
        (lane == 0) ? 0ull : (~0ull >> (64 - lane));
    const int rank_in_wave = __popcll(mm & ltmask);
    const int leader = __ffsll((unsigned long long)mm) - 1;
    if (lane == leader) hist[w][c] = __popcll(mm);
    __syncthreads();
    if (w == 0) {
        int tot = 0;
#pragma unroll
        for (int i = 0; i < 16; ++i) tot += hist[i][lane];
        int pre = tot;
#pragma unroll
        for (int off = 1; off < 64; off <<= 1) {
            const int t = __shfl_up(pre, off);
            if (lane >= off) pre += t;
        }
        startS[lane + 1] = pre;
        if (lane == 0) startS[0] = 0;
    }
    __syncthreads();
    int before = startS[c];
    for (int i = 0; i < w; ++i) before += hist[i][c];
    perm[g*kNPG + before + rank_in_wave] = g*kNPG + tid;
    if (tid < 65) startc[g*65 + tid] = startS[tid];
}

// ------------------------------------- K2: out = S^T x (+ vs2) — atomic-FREE
__global__ __launch_bounds__(1024) void k_pool_x(
    const float* __restrict__ x, const int* __restrict__ perm,
    const int* __restrict__ startc, const float* __restrict__ varr,
    float* __restrict__ out, float* __restrict__ vs2)
{
    const int tid  = threadIdx.x;
    const int g    = blockIdx.x >> 3;
    const int fh   = blockIdx.x & 7;
    const int w    = tid >> 6;
    const int lane = tid & 63;
    const int q    = lane & 7;      // feat quad (float4)
    const int sub  = lane >> 3;     // node slot 0..7
    const int fbase = fh*32 + q*4;
#pragma unroll
    for (int cc = 0; cc < 4; ++cc) {
        const int c = w*4 + cc;
        const int s = startc[g*65 + c];
        const int e = startc[g*65 + c + 1];
        float ax = 0.f, ay = 0.f, az = 0.f, aw = 0.f, v2 = 0.f;
        for (int base = s + sub; base < e; base += 8) {
            const int n = perm[(size_t)g*kNPG + base];
            const float v = varr[n];
            const float4 xv = *reinterpret_cast<const float4*>(
                x + (size_t)n*kF + fbase);
            ax = fmaf(v, xv.x, ax); ay = fmaf(v, xv.y, ay);
            az = fmaf(v, xv.z, az); aw = fmaf(v, xv.w, aw);
            v2 = fmaf(v, v, v2);
        }
#pragma unroll
        for (int off = 8; off < 64; off <<= 1) {
            ax += __shfl_xor(ax, off); ay += __shfl_xor(ay, off);
            az += __shfl_xor(az, off); aw += __shfl_xor(aw, off);
            v2 += __shfl_xor(v2, off);
        }
        if (sub == 0) {
            const float4 o = {ax, ay, az, aw};
            *reinterpret_cast<float4*>(
                out + OFF_OUT + (size_t)(g*kC + c)*kF + fbase) = o;
        }
        if (fh == 0 && lane == 0) vs2[g*kC + c] = v2;
    }
}

// ------------------------------------- K4: adjacency partials (+ a2 partial)
__global__ __launch_bounds__(1024) void k_adj(
    const int* __restrict__ ei, const float* __restrict__ ew,
    const int* __restrict__ carr, const float* __restrict__ varr,
    float* __restrict__ padj, float* __restrict__ a2p)
{
    __shared__ float adj[kC*kC];   // 16 KB
    __shared__ float vls[kNPG];    // 4 KB
    __shared__ int   cls[kNPG];    // 4 KB
    __shared__ float wred[16];
    const int tid = threadIdx.x;
    const int bid = blockIdx.x;             // 256 blocks = 64 graphs x 4
    const int g   = bid >> 2;
    for (int i = tid; i < kC*kC; i += 1024) adj[i] = 0.f;
    vls[tid] = varr[g*kNPG + tid];
    cls[tid] = carr[g*kNPG + tid];
    __syncthreads();
    const int e0 = bid * 8192;
    float a2l = 0.f;
#pragma unroll
    for (int it = 0; it < 8; ++it) {
        const int e  = e0 + it*1024 + tid;
        const int sn = ei[e]      & (kNPG - 1);
        const int dn = ei[kE + e] & (kNPG - 1);
        const float wv = ew[e];
        a2l += wv * wv;
        atomicAdd(&adj[cls[sn]*kC + cls[dn]], wv * vls[sn] * vls[dn]);
    }
    __syncthreads();
#pragma unroll
    for (int r = 0; r < 4; ++r) {
        const int lin = r*1024 + tid;
        padj[(size_t)bid*4096 + lin] = adj[lin];
    }
#pragma unroll
    for (int off = 32; off > 0; off >>= 1) a2l += __shfl_down(a2l, off);
    if ((tid & 63) == 0) wred[tid >> 6] = a2l;
    __syncthreads();
    if (tid == 0) {
        float s = 0.f;
#pragma unroll
        for (int wv = 0; wv < 16; ++wv) s += wred[wv];
        a2p[bid] = s;
    }
}

// ------------------------------------- K5: merge adjacency partials
__global__ __launch_bounds__(256) void k_adj_merge(
    const float* __restrict__ padj, float* __restrict__ out)
{
    const int id = blockIdx.x*256 + threadIdx.x;   // < 262144
    const int g = id >> 12, idx = id & 4095;
    float s = 0.f;
#pragma unroll
    for (int sp = 0; sp < 4; ++sp) s += padj[(size_t)(g*4 + sp)*4096 + idx];
    out[OFF_ADJ + id] = s;
}

// ------------------------------------- K6: link_loss scalar
__global__ __launch_bounds__(256) void k_final(
    const float* __restrict__ vs2, const float* __restrict__ a2p,
    float* __restrict__ out)
{
    const int tid = threadIdx.x;
    float p2l = 0.f, apl = 0.f;
#pragma unroll
    for (int r = 0; r < 16; ++r) {
        const int k = r*256 + tid;
        const float t = vs2[k];
        p2l += t*t;
        const int g = k >> 6, cc = k & 63;
        apl += out[OFF_ADJ + (size_t)g*4096 + cc*65];   // diagonal entries
    }
    float a2l = a2p[tid];
#pragma unroll
    for (int off = 32; off > 0; off >>= 1) {
        p2l += __shfl_down(p2l, off);
        apl += __shfl_down(apl, off);
        a2l += __shfl_down(a2l, off);
    }
    __shared__ float red[3][4];
    if ((tid & 63) == 0) {
        red[0][tid>>6] = p2l; red[1][tid>>6] = apl; red[2][tid>>6] = a2l;
    }
    __syncthreads();
    if (tid == 0) {
        const float p2 = red[0][0]+red[0][1]+red[0][2]+red[0][3];
        const float ap = red[1][0]+red[1][1]+red[1][2]+red[1][3];
        const float a2 = red[2][0]+red[2][1]+red[2][2]+red[2][3];
        const float val = a2 - 2.0f*ap + p2;
        out[OFF_LL] = sqrtf(fmaxf(val, 0.f)) / (float)kE;
        out[OFF_Z]  = 0.0f;
    }
}

// ----------------------------------------------------------------- launch
extern "C" void kernel_launch(void* const* d_in, const int* in_sizes, int n_in,
                              void* d_out, int out_size, void* d_ws, size_t ws_size,
                              hipStream_t stream)
{
    const float* x  = (const float*)d_in[0];
    const int*   ei = (const int*)d_in[1];
    const float* ew = (const float*)d_in[2];
    const float* Wm = (const float*)d_in[5];
    const float* bv = (const float*)d_in[6];
    float* out = (float*)d_out;
    char*  ws  = (char*)d_ws;
    int*   carr  = (int*)(ws + WS_C);
    float* varr  = (float*)(ws + WS_V);
    float* vs2   = (float*)(ws + WS_VS2);
    float* a2p   = (float*)(ws + WS_A2);
    int*   perm  = (int*)(ws + WS_PERM);
    int*   strt  = (int*)(ws + WS_STRT);
    float* padj  = (float*)(ws + WS_PADJ);

    k_const    <<<2065, 256, 0, stream>>>(out);
    k_logits   <<<512,   64, 0, stream>>>(x, Wm, bv, carr, varr);
    k_sort     <<<64,  1024, 0, stream>>>(carr, perm, strt);
    k_pool_x   <<<512, 1024, 0, stream>>>(x, perm, strt, varr, out, vs2);
    k_adj      <<<256, 1024, 0, stream>>>(ei, ew, carr, varr, padj, a2p);
    k_adj_merge<<<1024, 256, 0, stream>>>(padj, out);
    k_final    <<<1,    256, 0, stream>>>(vs2, a2p, out);
}